// Round 17
// baseline (44.730 us; speedup 1.0000x reference)
//
#include <hip/hip_runtime.h>
#include <hip/hip_cooperative_groups.h>
namespace cg = cooperative_groups;

#define NSEG 21
#define NLBL 20
#define DIM  32
#define NS   64      // slots per batch; 1024 px each
#define NT   512     // threads per block (8 waves)
#define NREP 16
#define DV   0.5f
#define DD   3.0f
#define BATCH 8
#define N_PIX 65536
#define SMS  36
#define TILE_B 65536
#define SEGT_B 1024
#define DYNB  (TILE_B + SEGT_B)

using short8 = __attribute__((ext_vector_type(8))) short;
using f32x4  = __attribute__((ext_vector_type(4))) float;

// ws float layout:
#define P_OFF  0                            // part  [B][32][20][NS]  327680
#define C2_OFF (BATCH*DIM*NLBL*NS)          // cpart [B][20][NS]       10240
#define M_OFF  (C2_OFF + BATCH*NLBL*NS)     // means [B][640]           5120
#define CN_OFF (M_OFF + BATCH*NLBL*DIM)     // cnt   [B][20]             160
#define VS_OFF (CN_OFF + BATCH*NLBL)        // vsum  [8][B][20] atomic  1280
#define BAR_OFF (VS_OFF + 8*BATCH*NLBL)     // ctrC[8]                     8
#define V_OFF  (BAR_OFF + 8)                // fallback vpart [B][20][NS] 10240
#define PB_OFF (V_OFF + BATCH*NLBL*NS)      // fallback pb [B][2]           16

__device__ __forceinline__ short bf16rne(float f) {
  const unsigned u = __builtin_bit_cast(unsigned, f);
  return (short)((u + 0x7FFFu + ((u >> 16) & 1u)) >> 16);
}

// ---- Stage A: MFMA segment sums+counts, 1024 px/block over 8 waves. ----
__device__ __forceinline__ void momentsBody(const float* __restrict__ emb,
                                            const int* __restrict__ seg,
                                            float* __restrict__ ws,
                                            float* lred, ushort* tile,
                                            unsigned char* segt,
                                            int bx, int b, int tid) {
  const int wv = tid >> 6, lane = tid & 63;
  const int lr = lane & 15, lg = lane >> 4;
  const float* rowA0 = emb + ((size_t)b * DIM + lr) * N_PIX;
  const float* rowA1 = rowA0 + (size_t)16 * N_PIX;
  const int*   segb  = seg + (size_t)b * N_PIX;

  f32x4 s00 = {0,0,0,0}, s01 = {0,0,0,0}, s10 = {0,0,0,0}, s11 = {0,0,0,0};
  f32x4 c0  = {0,0,0,0}, c1  = {0,0,0,0};
  short8 ones;
  #pragma unroll
  for (int j = 0; j < 8; ++j) ones[j] = (short)0x3F80;

  #pragma unroll
  for (int t = 0; t < 4; ++t) {
    const int kl = wv * 128 + t * 32 + lg * 8;   // local px 0..1023
    const int koff = bx * 1024 + kl;
    const float4 a00 = *(const float4*)(rowA0 + koff);
    const float4 a01 = *(const float4*)(rowA0 + koff + 4);
    const float4 a10 = *(const float4*)(rowA1 + koff);
    const float4 a11 = *(const float4*)(rowA1 + koff + 4);
    const int4   g0  = *(const int4*)(segb + koff);
    const int4   g1  = *(const int4*)(segb + koff + 4);

    short8 fa0, fa1, fb0, fb1;
    fa0[0] = bf16rne(a00.x); fa0[1] = bf16rne(a00.y);
    fa0[2] = bf16rne(a00.z); fa0[3] = bf16rne(a00.w);
    fa0[4] = bf16rne(a01.x); fa0[5] = bf16rne(a01.y);
    fa0[6] = bf16rne(a01.z); fa0[7] = bf16rne(a01.w);
    fa1[0] = bf16rne(a10.x); fa1[1] = bf16rne(a10.y);
    fa1[2] = bf16rne(a10.z); fa1[3] = bf16rne(a10.w);
    fa1[4] = bf16rne(a11.x); fa1[5] = bf16rne(a11.y);
    fa1[6] = bf16rne(a11.z); fa1[7] = bf16rne(a11.w);
    const int lab0 = lr + 1, lab1 = lr + 17;
    fb0[0] = (g0.x == lab0) ? (short)0x3F80 : (short)0;
    fb0[1] = (g0.y == lab0) ? (short)0x3F80 : (short)0;
    fb0[2] = (g0.z == lab0) ? (short)0x3F80 : (short)0;
    fb0[3] = (g0.w == lab0) ? (short)0x3F80 : (short)0;
    fb0[4] = (g1.x == lab0) ? (short)0x3F80 : (short)0;
    fb0[5] = (g1.y == lab0) ? (short)0x3F80 : (short)0;
    fb0[6] = (g1.z == lab0) ? (short)0x3F80 : (short)0;
    fb0[7] = (g1.w == lab0) ? (short)0x3F80 : (short)0;
    fb1[0] = (g0.x == lab1) ? (short)0x3F80 : (short)0;
    fb1[1] = (g0.y == lab1) ? (short)0x3F80 : (short)0;
    fb1[2] = (g0.z == lab1) ? (short)0x3F80 : (short)0;
    fb1[3] = (g0.w == lab1) ? (short)0x3F80 : (short)0;
    fb1[4] = (g1.x == lab1) ? (short)0x3F80 : (short)0;
    fb1[5] = (g1.y == lab1) ? (short)0x3F80 : (short)0;
    fb1[6] = (g1.z == lab1) ? (short)0x3F80 : (short)0;
    fb1[7] = (g1.w == lab1) ? (short)0x3F80 : (short)0;

    const int o = kl >> 3, om = o & 7;
    *(short8*)&tile[o * 256 + ((lr ^ om) << 3)] = fa0;
    *(short8*)&tile[o * 256 + (((lr ^ om) + 16) << 3)] = fa1;
    if (lr == 0) {
      unsigned long long pk =
          (unsigned long long)(g0.x & 255)        | ((unsigned long long)(g0.y & 255) << 8) |
          ((unsigned long long)(g0.z & 255) << 16) | ((unsigned long long)(g0.w & 255) << 24) |
          ((unsigned long long)(g1.x & 255) << 32) | ((unsigned long long)(g1.y & 255) << 40) |
          ((unsigned long long)(g1.z & 255) << 48) | ((unsigned long long)(g1.w & 255) << 56);
      *(unsigned long long*)&segt[o * 8] = pk;
    }

    s00 = __builtin_amdgcn_mfma_f32_16x16x32_bf16(fa0, fb0, s00, 0, 0, 0);
    s01 = __builtin_amdgcn_mfma_f32_16x16x32_bf16(fa0, fb1, s01, 0, 0, 0);
    s10 = __builtin_amdgcn_mfma_f32_16x16x32_bf16(fa1, fb0, s10, 0, 0, 0);
    s11 = __builtin_amdgcn_mfma_f32_16x16x32_bf16(fa1, fb1, s11, 0, 0, 0);
    c0  = __builtin_amdgcn_mfma_f32_16x16x32_bf16(ones, fb0, c0, 0, 0, 0);
    c1  = __builtin_amdgcn_mfma_f32_16x16x32_bf16(ones, fb1, c1, 0, 0, 0);
  }

  float vals[24];
  #pragma unroll
  for (int r = 0; r < 4; ++r) {
    vals[0 * 4 + r] = s00[r]; vals[1 * 4 + r] = s01[r];
    vals[2 * 4 + r] = s10[r]; vals[3 * 4 + r] = s11[r];
    vals[4 * 4 + r] = c0[r];  vals[5 * 4 + r] = c1[r];
  }
  #pragma unroll
  for (int w = 0; w < 8; ++w) {
    if (wv == w) {
      float* base = lred + lane * 4;
      if (w == 0) {
        #pragma unroll
        for (int f = 0; f < 6; ++f)
          #pragma unroll
          for (int r = 0; r < 4; ++r) base[f * 256 + r] = vals[f * 4 + r];
      } else {
        #pragma unroll
        for (int f = 0; f < 6; ++f)
          #pragma unroll
          for (int r = 0; r < 4; ++r) base[f * 256 + r] += vals[f * 4 + r];
      }
    }
    __syncthreads();
  }
  for (int i = tid; i < 1536; i += NT) {
    const float v = lred[i];
    const int f = i >> 8, ln = (i >> 2) & 63, r = i & 3;
    const int col = ln & 15, row = ((ln >> 4) << 2) | r;
    if (f < 4) {
      const int d = (f >> 1) * 16 + row;
      const int lcol = (f & 1) * 16 + col;
      if (lcol < NLBL)
        ws[P_OFF + (((size_t)(b * DIM + d) * NLBL) + lcol) * NS + bx] = v;
    } else {
      const int lcol = (f & 1) * 16 + col;
      if (row == 0 && lcol < NLBL)
        ws[C2_OFF + ((size_t)b * NLBL + lcol) * NS + bx] = v;
    }
  }
}

// ---- Stage B: canonical counts + means; 8 blocks per batch. ----
__device__ __forceinline__ void meansBody(float* __restrict__ ws, float* s_c,
                                          int bx8, int b, int tid) {
  if (tid < NLBL) {
    const float4* cp = (const float4*)(ws + C2_OFF + ((size_t)b * NLBL + tid) * NS);
    float q0 = 0.f, q1 = 0.f, q2 = 0.f, q3 = 0.f;
    #pragma unroll
    for (int k = 0; k < NS / 4; k += 4) {
      const float4 v0 = cp[k], v1 = cp[k + 1], v2 = cp[k + 2], v3 = cp[k + 3];
      q0 += v0.x + v0.y + v0.z + v0.w;
      q1 += v1.x + v1.y + v1.z + v1.w;
      q2 += v2.x + v2.y + v2.z + v2.w;
      q3 += v3.x + v3.y + v3.z + v3.w;
    }
    const float c = q0 + q1 + q2 + q3;
    if (bx8 == 0) ws[CN_OFF + b * NLBL + tid] = c;
    s_c[tid] = fmaxf(c, 1.f);
  }
  __syncthreads();
  if (tid < 80) {
    const int m = bx8 * 80 + tid;
    const int l = m >> 5, d = m & 31;
    const float4* pp = (const float4*)(ws + P_OFF + (((size_t)(b * DIM + d) * NLBL) + l) * NS);
    float q0 = 0.f, q1 = 0.f, q2 = 0.f, q3 = 0.f;
    #pragma unroll
    for (int k = 0; k < NS / 4; k += 4) {
      const float4 v0 = pp[k], v1 = pp[k + 1], v2 = pp[k + 2], v3 = pp[k + 3];
      q0 += v0.x + v0.y + v0.z + v0.w;
      q1 += v1.x + v1.y + v1.z + v1.w;
      q2 += v2.x + v2.y + v2.z + v2.w;
      q3 += v3.x + v3.y + v3.z + v3.w;
    }
    ws[M_OFF + (size_t)b * NLBL * DIM + m] = (q0 + q1 + q2 + q3) / s_c[l];
  }
}

// ---- means loader ----
__device__ __forceinline__ void loadMeans(const float* __restrict__ ws,
                                          float* s_m, int b, int tid, int nt) {
  for (int i = tid; i < NSEG * SMS; i += nt) s_m[i] = 0.f;
  __syncthreads();
  if (tid < 160) {
    const float4 v = ((const float4*)(ws + M_OFF + (size_t)b * NLBL * DIM))[tid];
    const int flat = tid * 4, l = flat >> 5, d = flat & 31;
    float* dst = &s_m[(l + 1) * SMS + d];
    dst[0] = v.x; dst[1] = v.y; dst[2] = v.z; dst[3] = v.w;
  }
}

// ---- var main from LDS tile (2 px/thread at NT=512). ----
__device__ __forceinline__ void varTileCompute(const ushort* tile,
                                               const unsigned char* segt,
                                               const float* s_m, float* s_v,
                                               int tid) {
  const int px0 = tid * 2;
  const int o = px0 >> 3, om = o & 7, p8 = px0 & 7;
  const int la0 = segt[px0], la1 = segt[px0 + 1];
  float q0 = 0.f, q1 = 0.f;
  #pragma unroll
  for (int db = 0; db < 8; ++db) {
    const f32x4 m0 = *(const f32x4*)&s_m[la0 * SMS + db * 4];
    const f32x4 m1 = *(const f32x4*)&s_m[la1 * SMS + db * 4];
    #pragma unroll
    for (int dd = 0; dd < 4; ++dd) {
      const int d = db * 4 + dd;
      const ushort2 ev = *(const ushort2*)&tile[o * 256 + ((d ^ om) << 3) + p8];
      float t;
      t = __builtin_bit_cast(float, (unsigned)ev.x << 16) - m0[dd]; q0 += t * t;
      t = __builtin_bit_cast(float, (unsigned)ev.y << 16) - m1[dd]; q1 += t * t;
    }
  }
  const int rb = (tid & (NREP - 1)) * NSEG;
  if (la0 > 0) { const float r = sqrtf(q0) - DV; if (r > 0.f) atomicAdd(&s_v[rb + la0], r * r); }
  if (la1 > 0) { const float r = sqrtf(q1) - DV; if (r > 0.f) atomicAdd(&s_v[rb + la1], r * r); }
}

// ---------------- fused cooperative kernel (512 threads, 2 grid syncs) ----------------
__global__ __launch_bounds__(NT, 4)
void k_fused(const float* __restrict__ emb, const int* __restrict__ seg,
             float* __restrict__ ws, float* __restrict__ out) {
  extern __shared__ __align__(16) char dynls[];
  ushort* tile = (ushort*)dynls;                          // 64KB
  unsigned char* segt = (unsigned char*)(dynls + TILE_B); // 1KB
  __shared__ __align__(16) float lred[1536];
  __shared__ __align__(16) float s_m[NSEG * SMS];
  __shared__ float s_v[NREP * NSEG];
  __shared__ float s_c[NLBL];
  __shared__ float s_vs[NLBL];
  __shared__ int   s_p[NLBL];
  __shared__ float s_red[8];
  __shared__ int   s_last;
  cg::grid_group gg = cg::this_grid();
  const int tid = threadIdx.x, bx = blockIdx.x, b = blockIdx.y;
  const int wv = tid >> 6, lane = tid & 63;

  momentsBody(emb, seg, ws, lred, tile, segt, bx, b, tid);
  gg.sync();

  if (bx < 8) meansBody(ws, s_c, bx, b, tid);
  gg.sync();

  // Stage C: var from resident tile; 8-slot replicated global accumulation
  for (int i = tid; i < NREP * NSEG; i += NT) s_v[i] = 0.f;
  loadMeans(ws, s_m, b, tid, NT);
  __syncthreads();
  varTileCompute(tile, segt, s_m, s_v, tid);
  __syncthreads();
  if (tid < NLBL) {
    float v = 0.f;
    #pragma unroll
    for (int r = 0; r < NREP; ++r) v += s_v[r * NSEG + (tid + 1)];
    atomicAdd(&ws[VS_OFF + ((size_t)(bx & 7) * BATCH + b) * NLBL + tid], v);
  }
  __syncthreads();
  if (tid == 0) {
    __threadfence();
    unsigned* ctr = (unsigned*)(ws + BAR_OFF);
    s_last = (atomicAdd(&ctr[b], 1u) == NS - 1) ? 1 : 0;
  }
  __syncthreads();

  // last arriver of batch b finalizes (s_m still resident) and adds to out
  if (s_last) {
    __threadfence();
    if (tid < 160) {
      const int g = tid >> 3, j = tid & 7;   // label, slot
      float s = atomicAdd(&ws[VS_OFF + ((size_t)j * BATCH + b) * NLBL + g], 0.f);
      s += __shfl_xor(s, 1, 64); s += __shfl_xor(s, 2, 64); s += __shfl_xor(s, 4, 64);
      if (j == 0) s_vs[g] = s;
    }
    if (tid < NLBL) {
      const float c = ws[CN_OFF + b * NLBL + tid];
      s_c[tid] = c;
      s_p[tid] = (c > 0.f) ? 1 : 0;
    }
    __syncthreads();
    float dl = 0.f;
    for (int p = tid; p < NLBL * NLBL; p += NT) {
      const int i = p / NLBL, j = p - (p / NLBL) * NLBL;
      if (i != j && s_p[i] && s_p[j]) {
        float sq = 0.f;
        #pragma unroll
        for (int d = 0; d < DIM; ++d) {
          const float t = s_m[(i + 1) * SMS + d] - s_m[(j + 1) * SMS + d];
          sq += t * t;
        }
        const float r = DD - sqrtf(sq);
        if (r > 0.f) dl += r * r;
      }
    }
    #pragma unroll
    for (int off = 32; off; off >>= 1) dl += __shfl_xor(dl, off, 64);
    if (lane == 0) s_red[wv] = dl;
    __syncthreads();
    if (tid == 0) {
      float dsum = 0.f;
      #pragma unroll
      for (int w = 0; w < 8; ++w) dsum += s_red[w];
      float nl = 0.f, var = 0.f;
      for (int l = 0; l < NLBL; ++l)
        if (s_p[l]) { nl += 1.f; var += s_vs[l] / s_c[l]; }
      const float vb  = (nl > 0.f) ? var / nl : 0.f;
      const float db_ = (nl > 1.f) ? dsum / fmaxf(nl * (nl - 1.f), 1.f) * 0.5f : 0.f;
      atomicAdd(&out[0], vb * (1.f / BATCH));
      atomicAdd(&out[1], db_ * (1.f / BATCH));
    }
  }
}

// ---------------- fallback discrete pipeline ----------------
__global__ __launch_bounds__(NT)
void k_moments(const float* __restrict__ emb, const int* __restrict__ seg,
               float* __restrict__ ws) {
  extern __shared__ __align__(16) char dynls[];
  ushort* tile = (ushort*)dynls;
  unsigned char* segt = (unsigned char*)(dynls + TILE_B);
  __shared__ __align__(16) float lred[1536];
  momentsBody(emb, seg, ws, lred, tile, segt, blockIdx.x, blockIdx.y, threadIdx.x);
}
__global__ __launch_bounds__(256)
void k_means(float* __restrict__ ws) {
  __shared__ float s_c[NLBL];
  meansBody(ws, s_c, blockIdx.x, blockIdx.y, threadIdx.x);
}
__global__ __launch_bounds__(256)
void k_varG(const float* __restrict__ emb, const int* __restrict__ seg,
            float* __restrict__ ws) {
  __shared__ __align__(16) float s_m[NSEG * SMS];
  __shared__ float s_v[NREP * NSEG];
  const int tid = threadIdx.x, bx = blockIdx.x, b = blockIdx.y;
  for (int i = tid; i < NREP * NSEG; i += 256) s_v[i] = 0.f;
  loadMeans(ws, s_m, b, tid, 256);
  __syncthreads();
  const int n0 = bx * 1024 + tid * 4;
  const int4 sl = *(const int4*)(seg + (size_t)b * N_PIX + n0);
  const float4* e4 = (const float4*)(emb + (size_t)b * DIM * N_PIX + n0);
  float q0 = 0.f, q1 = 0.f, q2 = 0.f, q3 = 0.f;
  #pragma unroll 8
  for (int d = 0; d < DIM; ++d) {
    const float4 e = e4[d * (N_PIX / 4)];
    float t;
    t = e.x - s_m[sl.x * SMS + d]; q0 += t * t;
    t = e.y - s_m[sl.y * SMS + d]; q1 += t * t;
    t = e.z - s_m[sl.z * SMS + d]; q2 += t * t;
    t = e.w - s_m[sl.w * SMS + d]; q3 += t * t;
  }
  const int rb = (tid & (NREP - 1)) * NSEG;
  if (sl.x > 0) { const float r = sqrtf(q0) - DV; if (r > 0.f) atomicAdd(&s_v[rb + sl.x], r * r); }
  if (sl.y > 0) { const float r = sqrtf(q1) - DV; if (r > 0.f) atomicAdd(&s_v[rb + sl.y], r * r); }
  if (sl.z > 0) { const float r = sqrtf(q2) - DV; if (r > 0.f) atomicAdd(&s_v[rb + sl.z], r * r); }
  if (sl.w > 0) { const float r = sqrtf(q3) - DV; if (r > 0.f) atomicAdd(&s_v[rb + sl.w], r * r); }
  __syncthreads();
  if (tid < NLBL) {
    float v = 0.f;
    #pragma unroll
    for (int r = 0; r < NREP; ++r) v += s_v[r * NSEG + (tid + 1)];
    ws[V_OFF + ((size_t)b * NLBL + tid) * NS + bx] = v;
  }
}
__global__ __launch_bounds__(256)
void k_final(float* __restrict__ ws) {
  __shared__ __align__(16) float s_m[NSEG * SMS];
  __shared__ float s_c[NLBL];
  __shared__ float s_vs[NLBL];
  __shared__ int   s_p[NLBL];
  __shared__ float s_red[4];
  const int b = blockIdx.x, tid = threadIdx.x;
  const int wv = tid >> 6, lane = tid & 63;
  loadMeans(ws, s_m, b, tid, 256);
  __syncthreads();
  if (tid < 160) {
    const int g = tid >> 3, j = tid & 7;
    const float4* v4 = (const float4*)(ws + V_OFF + ((size_t)b * NLBL + g) * NS + j * 8);
    const float4 a = v4[0], c = v4[1];
    float s = a.x + a.y + a.z + a.w + c.x + c.y + c.z + c.w;
    s += __shfl_xor(s, 1, 64); s += __shfl_xor(s, 2, 64); s += __shfl_xor(s, 4, 64);
    if (j == 0) s_vs[g] = s;
  }
  if (tid < NLBL) {
    const float c = ws[CN_OFF + b * NLBL + tid];
    s_c[tid] = c;
    s_p[tid] = (c > 0.f) ? 1 : 0;
  }
  __syncthreads();
  float dl = 0.f;
  for (int p = tid; p < NLBL * NLBL; p += 256) {
    const int i = p / NLBL, j = p - (p / NLBL) * NLBL;
    if (i != j && s_p[i] && s_p[j]) {
      float sq = 0.f;
      #pragma unroll
      for (int d = 0; d < DIM; ++d) {
        const float t = s_m[(i + 1) * SMS + d] - s_m[(j + 1) * SMS + d];
        sq += t * t;
      }
      const float r = DD - sqrtf(sq);
      if (r > 0.f) dl += r * r;
    }
  }
  #pragma unroll
  for (int off = 32; off; off >>= 1) dl += __shfl_xor(dl, off, 64);
  if (lane == 0) s_red[wv] = dl;
  __syncthreads();
  if (tid == 0) {
    const float dsum = s_red[0] + s_red[1] + s_red[2] + s_red[3];
    float nl = 0.f, var = 0.f;
    for (int l = 0; l < NLBL; ++l)
      if (s_p[l]) { nl += 1.f; var += s_vs[l] / s_c[l]; }
    ws[PB_OFF + b * 2]     = (nl > 0.f) ? var / nl : 0.f;
    ws[PB_OFF + b * 2 + 1] = (nl > 1.f) ? dsum / fmaxf(nl * (nl - 1.f), 1.f) * 0.5f : 0.f;
  }
}
__global__ __launch_bounds__(64)
void k_out(const float* __restrict__ ws, float* __restrict__ out) {
  const int tid = threadIdx.x;
  float v = 0.f, d = 0.f;
  if (tid < BATCH) {
    v = ws[PB_OFF + tid * 2];
    d = ws[PB_OFF + tid * 2 + 1];
  }
  #pragma unroll
  for (int off = 4; off; off >>= 1) { v += __shfl_xor(v, off, 64); d += __shfl_xor(d, off, 64); }
  if (tid == 0) {
    out[0] = v / (float)BATCH;
    out[1] = d / (float)BATCH;
    out[2] = 0.f;
  }
}

extern "C" void kernel_launch(void* const* d_in, const int* in_sizes, int n_in,
                              void* d_out, int out_size, void* d_ws, size_t ws_size,
                              hipStream_t stream) {
  const float* emb = (const float*)d_in[0];
  const int*   seg = (const int*)d_in[1];
  float* out = (float*)d_out;
  float* ws  = (float*)d_ws;

  int maxB = 0;
  bool coop = false;
  if (hipOccupancyMaxActiveBlocksPerMultiprocessor(&maxB, (const void*)k_fused, NT, DYNB)
        == hipSuccess)
    coop = ((long)maxB * 256 >= (long)NS * BATCH);
  if (coop) {
    hipMemsetAsync(ws + VS_OFF, 0, (8 * BATCH * NLBL + 8) * sizeof(float), stream);
    hipMemsetAsync(d_out, 0, (size_t)out_size * sizeof(float), stream);
    void* args[] = {(void*)&emb, (void*)&seg, (void*)&ws, (void*)&out};
    if (hipLaunchCooperativeKernel((const void*)k_fused, dim3(NS, BATCH), dim3(NT),
                                   args, DYNB, stream) == hipSuccess)
      return;
  }
  // fallback: discrete pipeline (identical math, global-read var pass)
  k_moments<<<dim3(NS, BATCH), NT, DYNB, stream>>>(emb, seg, ws);
  k_means  <<<dim3(8, BATCH), 256, 0, stream>>>(ws);
  k_varG   <<<dim3(NS, BATCH), 256, 0, stream>>>(emb, seg, ws);
  k_final  <<<dim3(BATCH), 256, 0, stream>>>(ws);
  k_out    <<<1, 64, 0, stream>>>(ws, out);
}

// Round 18
// 42.513 us; speedup vs baseline: 1.0522x; 1.0522x over previous
//
#include <hip/hip_runtime.h>
#include <hip/hip_cooperative_groups.h>
namespace cg = cooperative_groups;

#define NSEG 21
#define NLBL 20
#define DIM  32
#define NS   64      // slots per batch; 1024 px each
#define NREP 16
#define DV   0.5f
#define DD   3.0f
#define BATCH 8
#define N_PIX 65536
#define SMS  36
#define TILE_B 65536
#define SEGT_B 1024
#define DYNB  (TILE_B + SEGT_B)

using short8 = __attribute__((ext_vector_type(8))) short;
using f32x4  = __attribute__((ext_vector_type(4))) float;

// ws float layout:
#define P_OFF  0                            // part  [B][32][20][NS]  327680
#define C2_OFF (BATCH*DIM*NLBL*NS)          // cpart [B][20][NS]       10240
#define M_OFF  (C2_OFF + BATCH*NLBL*NS)     // means [B][640]           5120
#define CN_OFF (M_OFF + BATCH*NLBL*DIM)     // cnt   [B][20]             160
#define VS_OFF (CN_OFF + BATCH*NLBL)        // vsum  [8][B][20] atomic  1280
#define BAR_OFF (VS_OFF + 8*BATCH*NLBL)     // ctrC[8]                     8
#define V_OFF  (BAR_OFF + 8)                // fallback vpart [B][20][NS] 10240
#define PB_OFF (V_OFF + BATCH*NLBL*NS)      // fallback pb [B][2]           16

__device__ __forceinline__ short bf16rne(float f) {
  const unsigned u = __builtin_bit_cast(unsigned, f);
  return (short)((u + 0x7FFFu + ((u >> 16) & 1u)) >> 16);
}

// ---- Stage A: MFMA segment sums+counts, 1024 px/block; stashes bf16 tile. ----
__device__ __forceinline__ void momentsBody(const float* __restrict__ emb,
                                            const int* __restrict__ seg,
                                            float* __restrict__ ws,
                                            float* lred, ushort* tile,
                                            unsigned char* segt,
                                            int bx, int b, int tid) {
  const int wv = tid >> 6, lane = tid & 63;
  const int lr = lane & 15, lg = lane >> 4;
  const float* rowA0 = emb + ((size_t)b * DIM + lr) * N_PIX;
  const float* rowA1 = rowA0 + (size_t)16 * N_PIX;
  const int*   segb  = seg + (size_t)b * N_PIX;

  f32x4 s00 = {0,0,0,0}, s01 = {0,0,0,0}, s10 = {0,0,0,0}, s11 = {0,0,0,0};
  f32x4 c0  = {0,0,0,0}, c1  = {0,0,0,0};
  short8 ones;
  #pragma unroll
  for (int j = 0; j < 8; ++j) ones[j] = (short)0x3F80;

  #pragma unroll 2
  for (int t = 0; t < 8; ++t) {
    const int kl = wv * 256 + t * 32 + lg * 8;   // local px 0..1023
    const int koff = bx * 1024 + kl;
    const float4 a00 = *(const float4*)(rowA0 + koff);
    const float4 a01 = *(const float4*)(rowA0 + koff + 4);
    const float4 a10 = *(const float4*)(rowA1 + koff);
    const float4 a11 = *(const float4*)(rowA1 + koff + 4);
    const int4   g0  = *(const int4*)(segb + koff);
    const int4   g1  = *(const int4*)(segb + koff + 4);

    short8 fa0, fa1, fb0, fb1;
    fa0[0] = bf16rne(a00.x); fa0[1] = bf16rne(a00.y);
    fa0[2] = bf16rne(a00.z); fa0[3] = bf16rne(a00.w);
    fa0[4] = bf16rne(a01.x); fa0[5] = bf16rne(a01.y);
    fa0[6] = bf16rne(a01.z); fa0[7] = bf16rne(a01.w);
    fa1[0] = bf16rne(a10.x); fa1[1] = bf16rne(a10.y);
    fa1[2] = bf16rne(a10.z); fa1[3] = bf16rne(a10.w);
    fa1[4] = bf16rne(a11.x); fa1[5] = bf16rne(a11.y);
    fa1[6] = bf16rne(a11.z); fa1[7] = bf16rne(a11.w);
    const int lab0 = lr + 1, lab1 = lr + 17;
    fb0[0] = (g0.x == lab0) ? (short)0x3F80 : (short)0;
    fb0[1] = (g0.y == lab0) ? (short)0x3F80 : (short)0;
    fb0[2] = (g0.z == lab0) ? (short)0x3F80 : (short)0;
    fb0[3] = (g0.w == lab0) ? (short)0x3F80 : (short)0;
    fb0[4] = (g1.x == lab0) ? (short)0x3F80 : (short)0;
    fb0[5] = (g1.y == lab0) ? (short)0x3F80 : (short)0;
    fb0[6] = (g1.z == lab0) ? (short)0x3F80 : (short)0;
    fb0[7] = (g1.w == lab0) ? (short)0x3F80 : (short)0;
    fb1[0] = (g0.x == lab1) ? (short)0x3F80 : (short)0;
    fb1[1] = (g0.y == lab1) ? (short)0x3F80 : (short)0;
    fb1[2] = (g0.z == lab1) ? (short)0x3F80 : (short)0;
    fb1[3] = (g0.w == lab1) ? (short)0x3F80 : (short)0;
    fb1[4] = (g1.x == lab1) ? (short)0x3F80 : (short)0;
    fb1[5] = (g1.y == lab1) ? (short)0x3F80 : (short)0;
    fb1[6] = (g1.z == lab1) ? (short)0x3F80 : (short)0;
    fb1[7] = (g1.w == lab1) ? (short)0x3F80 : (short)0;

    const int o = kl >> 3, om = o & 7;
    *(short8*)&tile[o * 256 + ((lr ^ om) << 3)] = fa0;
    *(short8*)&tile[o * 256 + (((lr ^ om) + 16) << 3)] = fa1;
    if (lr == 0) {
      unsigned long long pk =
          (unsigned long long)(g0.x & 255)        | ((unsigned long long)(g0.y & 255) << 8) |
          ((unsigned long long)(g0.z & 255) << 16) | ((unsigned long long)(g0.w & 255) << 24) |
          ((unsigned long long)(g1.x & 255) << 32) | ((unsigned long long)(g1.y & 255) << 40) |
          ((unsigned long long)(g1.z & 255) << 48) | ((unsigned long long)(g1.w & 255) << 56);
      *(unsigned long long*)&segt[o * 8] = pk;
    }

    s00 = __builtin_amdgcn_mfma_f32_16x16x32_bf16(fa0, fb0, s00, 0, 0, 0);
    s01 = __builtin_amdgcn_mfma_f32_16x16x32_bf16(fa0, fb1, s01, 0, 0, 0);
    s10 = __builtin_amdgcn_mfma_f32_16x16x32_bf16(fa1, fb0, s10, 0, 0, 0);
    s11 = __builtin_amdgcn_mfma_f32_16x16x32_bf16(fa1, fb1, s11, 0, 0, 0);
    c0  = __builtin_amdgcn_mfma_f32_16x16x32_bf16(ones, fb0, c0, 0, 0, 0);
    c1  = __builtin_amdgcn_mfma_f32_16x16x32_bf16(ones, fb1, c1, 0, 0, 0);
  }

  float vals[24];
  #pragma unroll
  for (int r = 0; r < 4; ++r) {
    vals[0 * 4 + r] = s00[r]; vals[1 * 4 + r] = s01[r];
    vals[2 * 4 + r] = s10[r]; vals[3 * 4 + r] = s11[r];
    vals[4 * 4 + r] = c0[r];  vals[5 * 4 + r] = c1[r];
  }
  #pragma unroll
  for (int w = 0; w < 4; ++w) {
    if (wv == w) {
      float* base = lred + lane * 4;
      if (w == 0) {
        #pragma unroll
        for (int f = 0; f < 6; ++f)
          #pragma unroll
          for (int r = 0; r < 4; ++r) base[f * 256 + r] = vals[f * 4 + r];
      } else {
        #pragma unroll
        for (int f = 0; f < 6; ++f)
          #pragma unroll
          for (int r = 0; r < 4; ++r) base[f * 256 + r] += vals[f * 4 + r];
      }
    }
    __syncthreads();
  }
  for (int i = tid; i < 1536; i += 256) {
    const float v = lred[i];
    const int f = i >> 8, ln = (i >> 2) & 63, r = i & 3;
    const int col = ln & 15, row = ((ln >> 4) << 2) | r;
    if (f < 4) {
      const int d = (f >> 1) * 16 + row;
      const int lcol = (f & 1) * 16 + col;
      if (lcol < NLBL)
        ws[P_OFF + (((size_t)(b * DIM + d) * NLBL) + lcol) * NS + bx] = v;
    } else {
      const int lcol = (f & 1) * 16 + col;
      if (row == 0 && lcol < NLBL)
        ws[C2_OFF + ((size_t)b * NLBL + lcol) * NS + bx] = v;
    }
  }
}

// ---- Stage B: canonical counts + means; 8 blocks per batch. ----
__device__ __forceinline__ void meansBody(float* __restrict__ ws, float* s_c,
                                          int bx8, int b, int tid) {
  if (tid < NLBL) {
    const float4* cp = (const float4*)(ws + C2_OFF + ((size_t)b * NLBL + tid) * NS);
    float q0 = 0.f, q1 = 0.f, q2 = 0.f, q3 = 0.f;
    #pragma unroll
    for (int k = 0; k < NS / 4; k += 4) {
      const float4 v0 = cp[k], v1 = cp[k + 1], v2 = cp[k + 2], v3 = cp[k + 3];
      q0 += v0.x + v0.y + v0.z + v0.w;
      q1 += v1.x + v1.y + v1.z + v1.w;
      q2 += v2.x + v2.y + v2.z + v2.w;
      q3 += v3.x + v3.y + v3.z + v3.w;
    }
    const float c = q0 + q1 + q2 + q3;
    if (bx8 == 0) ws[CN_OFF + b * NLBL + tid] = c;
    s_c[tid] = fmaxf(c, 1.f);
  }
  __syncthreads();
  if (tid < 80) {
    const int m = bx8 * 80 + tid;
    const int l = m >> 5, d = m & 31;
    const float4* pp = (const float4*)(ws + P_OFF + (((size_t)(b * DIM + d) * NLBL) + l) * NS);
    float q0 = 0.f, q1 = 0.f, q2 = 0.f, q3 = 0.f;
    #pragma unroll
    for (int k = 0; k < NS / 4; k += 4) {
      const float4 v0 = pp[k], v1 = pp[k + 1], v2 = pp[k + 2], v3 = pp[k + 3];
      q0 += v0.x + v0.y + v0.z + v0.w;
      q1 += v1.x + v1.y + v1.z + v1.w;
      q2 += v2.x + v2.y + v2.z + v2.w;
      q3 += v3.x + v3.y + v3.z + v3.w;
    }
    ws[M_OFF + (size_t)b * NLBL * DIM + m] = (q0 + q1 + q2 + q3) / s_c[l];
  }
}

// ---- means loader ----
__device__ __forceinline__ void loadMeans(const float* __restrict__ ws,
                                          float* s_m, int b, int tid) {
  for (int i = tid; i < NSEG * SMS; i += 256) s_m[i] = 0.f;
  __syncthreads();
  if (tid < 160) {
    const float4 v = ((const float4*)(ws + M_OFF + (size_t)b * NLBL * DIM))[tid];
    const int flat = tid * 4, l = flat >> 5, d = flat & 31;
    float* dst = &s_m[(l + 1) * SMS + d];
    dst[0] = v.x; dst[1] = v.y; dst[2] = v.z; dst[3] = v.w;
  }
}

// ---- var main from LDS tile (4 px/thread). ----
__device__ __forceinline__ void varTileCompute(const ushort* tile,
                                               const unsigned char* segt,
                                               const float* s_m, float* s_v,
                                               int tid) {
  const int px0 = tid * 4;
  const int o = px0 >> 3, om = o & 7, p8 = px0 & 7;
  const int la0 = segt[px0], la1 = segt[px0 + 1], la2 = segt[px0 + 2], la3 = segt[px0 + 3];
  float q0 = 0.f, q1 = 0.f, q2 = 0.f, q3 = 0.f;
  #pragma unroll
  for (int db = 0; db < 8; ++db) {
    const f32x4 m0 = *(const f32x4*)&s_m[la0 * SMS + db * 4];
    const f32x4 m1 = *(const f32x4*)&s_m[la1 * SMS + db * 4];
    const f32x4 m2 = *(const f32x4*)&s_m[la2 * SMS + db * 4];
    const f32x4 m3 = *(const f32x4*)&s_m[la3 * SMS + db * 4];
    #pragma unroll
    for (int dd = 0; dd < 4; ++dd) {
      const int d = db * 4 + dd;
      const ushort4 ev = *(const ushort4*)&tile[o * 256 + ((d ^ om) << 3) + p8];
      float t;
      t = __builtin_bit_cast(float, (unsigned)ev.x << 16) - m0[dd]; q0 += t * t;
      t = __builtin_bit_cast(float, (unsigned)ev.y << 16) - m1[dd]; q1 += t * t;
      t = __builtin_bit_cast(float, (unsigned)ev.z << 16) - m2[dd]; q2 += t * t;
      t = __builtin_bit_cast(float, (unsigned)ev.w << 16) - m3[dd]; q3 += t * t;
    }
  }
  const int rb = (tid & (NREP - 1)) * NSEG;
  if (la0 > 0) { const float r = sqrtf(q0) - DV; if (r > 0.f) atomicAdd(&s_v[rb + la0], r * r); }
  if (la1 > 0) { const float r = sqrtf(q1) - DV; if (r > 0.f) atomicAdd(&s_v[rb + la1], r * r); }
  if (la2 > 0) { const float r = sqrtf(q2) - DV; if (r > 0.f) atomicAdd(&s_v[rb + la2], r * r); }
  if (la3 > 0) { const float r = sqrtf(q3) - DV; if (r > 0.f) atomicAdd(&s_v[rb + la3], r * r); }
}

// ---------------- fused cooperative kernel (2 grid syncs, 1 graph node) ----------------
__global__ __launch_bounds__(256, 2)
void k_fused(const float* __restrict__ emb, const int* __restrict__ seg,
             float* __restrict__ ws, float* __restrict__ out) {
  extern __shared__ __align__(16) char dynls[];
  ushort* tile = (ushort*)dynls;                          // 64KB
  unsigned char* segt = (unsigned char*)(dynls + TILE_B); // 1KB
  __shared__ __align__(16) float lred[1536];
  __shared__ __align__(16) float s_m[NSEG * SMS];
  __shared__ float s_v[NREP * NSEG];
  __shared__ float s_c[NLBL];
  __shared__ float s_vs[NLBL];
  __shared__ int   s_p[NLBL];
  __shared__ float s_red[4];
  __shared__ int   s_last;
  cg::grid_group gg = cg::this_grid();
  const int tid = threadIdx.x, bx = blockIdx.x, b = blockIdx.y;
  const int wv = tid >> 6, lane = tid & 63;

  // in-kernel zeroing (consumers are all ≥2 gg.syncs later)
  if (bx < 8 && tid < NLBL)
    ws[VS_OFF + ((size_t)bx * BATCH + b) * NLBL + tid] = 0.f;
  if (bx == 8 && tid == 0) ((unsigned*)(ws + BAR_OFF))[b] = 0u;
  if (bx == 9 && b == 0 && tid < 3) out[tid] = 0.f;

  momentsBody(emb, seg, ws, lred, tile, segt, bx, b, tid);
  gg.sync();

  if (bx < 8) meansBody(ws, s_c, bx, b, tid);
  gg.sync();

  // Stage C: var from resident tile; 8-slot replicated global accumulation
  for (int i = tid; i < NREP * NSEG; i += 256) s_v[i] = 0.f;
  loadMeans(ws, s_m, b, tid);
  __syncthreads();
  varTileCompute(tile, segt, s_m, s_v, tid);
  __syncthreads();
  if (tid < NLBL) {
    float v = 0.f;
    #pragma unroll
    for (int r = 0; r < NREP; ++r) v += s_v[r * NSEG + (tid + 1)];
    atomicAdd(&ws[VS_OFF + ((size_t)(bx & 7) * BATCH + b) * NLBL + tid], v);
  }
  __syncthreads();
  if (tid == 0) {
    __threadfence();
    unsigned* ctr = (unsigned*)(ws + BAR_OFF);
    s_last = (atomicAdd(&ctr[b], 1u) == NS - 1) ? 1 : 0;
  }
  __syncthreads();

  // last arriver of batch b finalizes (s_m still resident) and adds to out
  if (s_last) {
    __threadfence();
    if (tid < 160) {
      const int g = tid >> 3, j = tid & 7;   // label, slot
      float s = atomicAdd(&ws[VS_OFF + ((size_t)j * BATCH + b) * NLBL + g], 0.f);
      s += __shfl_xor(s, 1, 64); s += __shfl_xor(s, 2, 64); s += __shfl_xor(s, 4, 64);
      if (j == 0) s_vs[g] = s;
    }
    if (tid < NLBL) {
      const float c = ws[CN_OFF + b * NLBL + tid];
      s_c[tid] = c;
      s_p[tid] = (c > 0.f) ? 1 : 0;
    }
    __syncthreads();
    float dl = 0.f;
    for (int p = tid; p < NLBL * NLBL; p += 256) {
      const int i = p / NLBL, j = p - (p / NLBL) * NLBL;
      if (i != j && s_p[i] && s_p[j]) {
        float sq = 0.f;
        #pragma unroll
        for (int d = 0; d < DIM; ++d) {
          const float t = s_m[(i + 1) * SMS + d] - s_m[(j + 1) * SMS + d];
          sq += t * t;
        }
        const float r = DD - sqrtf(sq);
        if (r > 0.f) dl += r * r;
      }
    }
    #pragma unroll
    for (int off = 32; off; off >>= 1) dl += __shfl_xor(dl, off, 64);
    if (lane == 0) s_red[wv] = dl;
    __syncthreads();
    if (tid == 0) {
      const float dsum = s_red[0] + s_red[1] + s_red[2] + s_red[3];
      float nl = 0.f, var = 0.f;
      for (int l = 0; l < NLBL; ++l)
        if (s_p[l]) { nl += 1.f; var += s_vs[l] / s_c[l]; }
      const float vb  = (nl > 0.f) ? var / nl : 0.f;
      const float db_ = (nl > 1.f) ? dsum / fmaxf(nl * (nl - 1.f), 1.f) * 0.5f : 0.f;
      atomicAdd(&out[0], vb * (1.f / BATCH));
      atomicAdd(&out[1], db_ * (1.f / BATCH));
    }
  }
}

// ---------------- fallback discrete pipeline ----------------
__global__ __launch_bounds__(256)
void k_moments(const float* __restrict__ emb, const int* __restrict__ seg,
               float* __restrict__ ws) {
  extern __shared__ __align__(16) char dynls[];
  ushort* tile = (ushort*)dynls;
  unsigned char* segt = (unsigned char*)(dynls + TILE_B);
  __shared__ __align__(16) float lred[1536];
  momentsBody(emb, seg, ws, lred, tile, segt, blockIdx.x, blockIdx.y, threadIdx.x);
}
__global__ __launch_bounds__(256)
void k_means(float* __restrict__ ws) {
  __shared__ float s_c[NLBL];
  meansBody(ws, s_c, blockIdx.x, blockIdx.y, threadIdx.x);
}
__global__ __launch_bounds__(256)
void k_varG(const float* __restrict__ emb, const int* __restrict__ seg,
            float* __restrict__ ws) {
  __shared__ __align__(16) float s_m[NSEG * SMS];
  __shared__ float s_v[NREP * NSEG];
  const int tid = threadIdx.x, bx = blockIdx.x, b = blockIdx.y;
  for (int i = tid; i < NREP * NSEG; i += 256) s_v[i] = 0.f;
  loadMeans(ws, s_m, b, tid);
  __syncthreads();
  const int n0 = bx * 1024 + tid * 4;
  const int4 sl = *(const int4*)(seg + (size_t)b * N_PIX + n0);
  const float4* e4 = (const float4*)(emb + (size_t)b * DIM * N_PIX + n0);
  float q0 = 0.f, q1 = 0.f, q2 = 0.f, q3 = 0.f;
  #pragma unroll 8
  for (int d = 0; d < DIM; ++d) {
    const float4 e = e4[d * (N_PIX / 4)];
    float t;
    t = e.x - s_m[sl.x * SMS + d]; q0 += t * t;
    t = e.y - s_m[sl.y * SMS + d]; q1 += t * t;
    t = e.z - s_m[sl.z * SMS + d]; q2 += t * t;
    t = e.w - s_m[sl.w * SMS + d]; q3 += t * t;
  }
  const int rb = (tid & (NREP - 1)) * NSEG;
  if (sl.x > 0) { const float r = sqrtf(q0) - DV; if (r > 0.f) atomicAdd(&s_v[rb + sl.x], r * r); }
  if (sl.y > 0) { const float r = sqrtf(q1) - DV; if (r > 0.f) atomicAdd(&s_v[rb + sl.y], r * r); }
  if (sl.z > 0) { const float r = sqrtf(q2) - DV; if (r > 0.f) atomicAdd(&s_v[rb + sl.z], r * r); }
  if (sl.w > 0) { const float r = sqrtf(q3) - DV; if (r > 0.f) atomicAdd(&s_v[rb + sl.w], r * r); }
  __syncthreads();
  if (tid < NLBL) {
    float v = 0.f;
    #pragma unroll
    for (int r = 0; r < NREP; ++r) v += s_v[r * NSEG + (tid + 1)];
    ws[V_OFF + ((size_t)b * NLBL + tid) * NS + bx] = v;
  }
}
__global__ __launch_bounds__(256)
void k_final(float* __restrict__ ws) {
  __shared__ __align__(16) float s_m[NSEG * SMS];
  __shared__ float s_c[NLBL];
  __shared__ float s_vs[NLBL];
  __shared__ int   s_p[NLBL];
  __shared__ float s_red[4];
  const int b = blockIdx.x, tid = threadIdx.x;
  const int wv = tid >> 6, lane = tid & 63;
  loadMeans(ws, s_m, b, tid);
  __syncthreads();
  if (tid < 160) {
    const int g = tid >> 3, j = tid & 7;
    const float4* v4 = (const float4*)(ws + V_OFF + ((size_t)b * NLBL + g) * NS + j * 8);
    const float4 a = v4[0], c = v4[1];
    float s = a.x + a.y + a.z + a.w + c.x + c.y + c.z + c.w;
    s += __shfl_xor(s, 1, 64); s += __shfl_xor(s, 2, 64); s += __shfl_xor(s, 4, 64);
    if (j == 0) s_vs[g] = s;
  }
  if (tid < NLBL) {
    const float c = ws[CN_OFF + b * NLBL + tid];
    s_c[tid] = c;
    s_p[tid] = (c > 0.f) ? 1 : 0;
  }
  __syncthreads();
  float dl = 0.f;
  for (int p = tid; p < NLBL * NLBL; p += 256) {
    const int i = p / NLBL, j = p - (p / NLBL) * NLBL;
    if (i != j && s_p[i] && s_p[j]) {
      float sq = 0.f;
      #pragma unroll
      for (int d = 0; d < DIM; ++d) {
        const float t = s_m[(i + 1) * SMS + d] - s_m[(j + 1) * SMS + d];
        sq += t * t;
      }
      const float r = DD - sqrtf(sq);
      if (r > 0.f) dl += r * r;
    }
  }
  #pragma unroll
  for (int off = 32; off; off >>= 1) dl += __shfl_xor(dl, off, 64);
  if (lane == 0) s_red[wv] = dl;
  __syncthreads();
  if (tid == 0) {
    const float dsum = s_red[0] + s_red[1] + s_red[2] + s_red[3];
    float nl = 0.f, var = 0.f;
    for (int l = 0; l < NLBL; ++l)
      if (s_p[l]) { nl += 1.f; var += s_vs[l] / s_c[l]; }
    ws[PB_OFF + b * 2]     = (nl > 0.f) ? var / nl : 0.f;
    ws[PB_OFF + b * 2 + 1] = (nl > 1.f) ? dsum / fmaxf(nl * (nl - 1.f), 1.f) * 0.5f : 0.f;
  }
}
__global__ __launch_bounds__(64)
void k_out(const float* __restrict__ ws, float* __restrict__ out) {
  const int tid = threadIdx.x;
  float v = 0.f, d = 0.f;
  if (tid < BATCH) {
    v = ws[PB_OFF + tid * 2];
    d = ws[PB_OFF + tid * 2 + 1];
  }
  #pragma unroll
  for (int off = 4; off; off >>= 1) { v += __shfl_xor(v, off, 64); d += __shfl_xor(d, off, 64); }
  if (tid == 0) {
    out[0] = v / (float)BATCH;
    out[1] = d / (float)BATCH;
    out[2] = 0.f;
  }
}

extern "C" void kernel_launch(void* const* d_in, const int* in_sizes, int n_in,
                              void* d_out, int out_size, void* d_ws, size_t ws_size,
                              hipStream_t stream) {
  const float* emb = (const float*)d_in[0];
  const int*   seg = (const int*)d_in[1];
  float* out = (float*)d_out;
  float* ws  = (float*)d_ws;

  int maxB = 0;
  bool coop = false;
  if (hipOccupancyMaxActiveBlocksPerMultiprocessor(&maxB, (const void*)k_fused, 256, DYNB)
        == hipSuccess)
    coop = ((long)maxB * 256 >= (long)NS * BATCH);
  if (coop) {
    void* args[] = {(void*)&emb, (void*)&seg, (void*)&ws, (void*)&out};
    if (hipLaunchCooperativeKernel((const void*)k_fused, dim3(NS, BATCH), dim3(256),
                                   args, DYNB, stream) == hipSuccess)
      return;
  }
  // fallback: discrete pipeline (identical math, global-read var pass)
  k_moments<<<dim3(NS, BATCH), 256, DYNB, stream>>>(emb, seg, ws);
  k_means  <<<dim3(8, BATCH), 256, 0, stream>>>(ws);
  k_varG   <<<dim3(NS, BATCH), 256, 0, stream>>>(emb, seg, ws);
  k_final  <<<dim3(BATCH), 256, 0, stream>>>(ws);
  k_out    <<<1, 64, 0, stream>>>(ws, out);
}